// Round 1
// baseline (931.310 us; speedup 1.0000x reference)
//
#include <hip/hip_runtime.h>
#include <hip/hip_bf16.h>

// Problem constants: B=2, S=2048, H=1024, G=256, E=8, M=2048, TOP_K=2
#define T_TOK 4096      // B*S
#define N_PAIR 8192     // T_TOK * 2
#define H_DIM 1024
#define M_DIM 2048
#define E_NUM 8

using bf16x8 = __attribute__((ext_vector_type(8))) short;
using f32x4  = __attribute__((ext_vector_type(4))) float;

__device__ __forceinline__ unsigned short f2bf(float f) {
    unsigned int u = __builtin_bit_cast(unsigned int, f);
    u += 0x7fffu + ((u >> 16) & 1u);   // RNE
    return (unsigned short)(u >> 16);
}

// ---- K0: genre gate per (b,e) with both biases folded; zero meta[24] ----
__global__ void k_init(const float* __restrict__ genre, const float* __restrict__ gg_W,
                       const float* __restrict__ gg_b, const float* __restrict__ wg_b,
                       float* __restrict__ genreE, int* __restrict__ meta)
{
    int t = threadIdx.x;
    if (t < 16) {
        int b = t >> 3, e = t & 7;
        float s = wg_b[e] + gg_b[e];
        for (int gi = 0; gi < 256; gi++) s += genre[b * 256 + gi] * gg_W[gi * 8 + e];
        genreE[t] = s;
    }
    if (t >= 32 && t < 56) meta[t - 32] = 0;  // counts[8], bases[8], fills[8]
}

// ---- K1: RMSNorm + word gate + softmax + top2. One wave per token. ----
__global__ void k_routing(const float* __restrict__ x, const float* __restrict__ rms_w,
                          const float* __restrict__ wg_W, const float* __restrict__ genreE,
                          int* __restrict__ tok_e, float* __restrict__ tok_w,
                          int* __restrict__ meta)
{
    int wave = threadIdx.x >> 6, lane = threadIdx.x & 63;
    int t = blockIdx.x * 4 + wave;
    const float* xr = x + (size_t)t * H_DIM;
    float xv[16];
    float ss = 0.f;
#pragma unroll
    for (int j = 0; j < 16; j++) { xv[j] = xr[lane + 64 * j]; ss += xv[j] * xv[j]; }
#pragma unroll
    for (int off = 32; off > 0; off >>= 1) ss += __shfl_xor(ss, off);
    float rstd = rsqrtf(ss * (1.f / 1024.f) + 1e-6f);
    float g[8] = {0.f, 0.f, 0.f, 0.f, 0.f, 0.f, 0.f, 0.f};
#pragma unroll
    for (int j = 0; j < 16; j++) {
        int h = lane + 64 * j;
        float xn = xv[j] * rstd * rms_w[h];
        const float4* w4 = (const float4*)(wg_W + h * 8);
        float4 wa = w4[0], wb = w4[1];
        g[0] += xn * wa.x; g[1] += xn * wa.y; g[2] += xn * wa.z; g[3] += xn * wa.w;
        g[4] += xn * wb.x; g[5] += xn * wb.y; g[6] += xn * wb.z; g[7] += xn * wb.w;
    }
#pragma unroll
    for (int e = 0; e < 8; e++) {
#pragma unroll
        for (int off = 32; off > 0; off >>= 1) g[e] += __shfl_xor(g[e], off);
    }
    if (lane == 0) {
        int b = t >> 11;
#pragma unroll
        for (int e = 0; e < 8; e++) g[e] += genreE[b * 8 + e];
        float m = g[0];
        for (int e = 1; e < 8; e++) m = fmaxf(m, g[e]);
        float p[8], psum = 0.f;
        for (int e = 0; e < 8; e++) { p[e] = expf(g[e] - m); psum += p[e]; }
        int i0 = 0;
        for (int e = 1; e < 8; e++) if (p[e] > p[i0]) i0 = e;
        int i1 = (i0 == 0) ? 1 : 0;
        for (int e = 0; e < 8; e++) if (e != i0 && p[e] > p[i1]) i1 = e;
        float inv = 1.f / psum;
        tok_e[t * 2] = i0;     tok_e[t * 2 + 1] = i1;
        tok_w[t * 2] = p[i0] * inv; tok_w[t * 2 + 1] = p[i1] * inv;
        atomicAdd(&meta[i0], 1);
        atomicAdd(&meta[i1], 1);
    }
}

// ---- K2: exclusive prefix sum over 8 counts ----
__global__ void k_scan(int* __restrict__ meta)
{
    if (threadIdx.x == 0) {
        int acc = 0;
        for (int e = 0; e < 8; e++) { meta[8 + e] = acc; meta[16 + e] = acc; acc += meta[e]; }
    }
}

// ---- K3: gather token rows (fp32 -> bf16) into expert-sorted order. One wave/pair. ----
__global__ void k_gather(const float* __restrict__ x, const int* __restrict__ tok_e,
                         const float* __restrict__ tok_w, int* __restrict__ meta,
                         int* __restrict__ pair_token, float* __restrict__ pair_w,
                         unsigned short* __restrict__ x_g)
{
    int wave = threadIdx.x >> 6, lane = threadIdx.x & 63;
    int p = blockIdx.x * 4 + wave;
    int t = p >> 1, k = p & 1;
    int e = tok_e[t * 2 + k];
    int pos;
    if (lane == 0) {
        pos = atomicAdd(&meta[16 + e], 1);
        pair_token[pos] = t;
        pair_w[pos] = tok_w[t * 2 + k];
    }
    pos = __shfl(pos, 0);
    const float4* src = (const float4*)(x + (size_t)t * H_DIM);
    ushort4* dst = (ushort4*)(x_g + (size_t)pos * H_DIM);
#pragma unroll
    for (int j = 0; j < 4; j++) {
        float4 v = src[lane + 64 * j];
        ushort4 o;
        o.x = f2bf(v.x); o.y = f2bf(v.y); o.z = f2bf(v.z); o.w = f2bf(v.w);
        dst[lane + 64 * j] = o;
    }
}

// ---- K4: transpose-convert weights [E][K][N] fp32 -> [E][N][K] bf16 ----
__global__ void k_transw(const float* __restrict__ W, unsigned short* __restrict__ Wt,
                         int K, int N)
{
    __shared__ float ld[32][33];
    size_t eoff = (size_t)blockIdx.z * K * N;
    int k0 = blockIdx.y * 32, n0 = blockIdx.x * 32;
    int t = threadIdx.x;
    {
        int kk = t >> 3, nc = t & 7;
        float4 v = *(const float4*)(W + eoff + (size_t)(k0 + kk) * N + n0 + nc * 4);
        ld[kk][nc * 4 + 0] = v.x; ld[kk][nc * 4 + 1] = v.y;
        ld[kk][nc * 4 + 2] = v.z; ld[kk][nc * 4 + 3] = v.w;
    }
    __syncthreads();
    {
        int nn = t >> 3, kc = t & 7;
        ushort4 o;
        o.x = f2bf(ld[kc * 4 + 0][nn]); o.y = f2bf(ld[kc * 4 + 1][nn]);
        o.z = f2bf(ld[kc * 4 + 2][nn]); o.w = f2bf(ld[kc * 4 + 3][nn]);
        *(ushort4*)(Wt + eoff + (size_t)(n0 + nn) * K + k0 + kc * 4) = o;
    }
}

// ---- GEMM: C[seg rows x N] = A_seg @ Wt[e]^T (+bias, relu) ; optional scatter ----
// A: bf16 [P][K] expert-sorted rows; Wt: bf16 [E][N][K]; 128x128 tile, BK=32,
// 4 waves each 64x64 (4x4 of 16x16x32 MFMA).
template<bool RELU, bool SCATTER>
__global__ void k_gemm(const unsigned short* __restrict__ A,
                       const unsigned short* __restrict__ Wt,
                       const float* __restrict__ bias,
                       unsigned short* __restrict__ Cout,
                       float* __restrict__ outF,
                       const int* __restrict__ meta,
                       const int* __restrict__ pair_token,
                       const float* __restrict__ pair_w,
                       int K, int N)
{
    int e = blockIdx.z;
    int cnt = meta[e];
    int by = blockIdx.y;
    if (by * 128 >= cnt) return;
    int base = meta[8 + e];
    int bx = blockIdx.x;

    __shared__ __align__(16) unsigned short As[128][40];
    __shared__ __align__(16) unsigned short Bs[128][40];

    const unsigned short* Aseg = A + (size_t)base * K;
    const unsigned short* Bw   = Wt + (size_t)e * N * K + (size_t)bx * 128 * K;

    int tid = threadIdx.x;
    int wave = tid >> 6, lane = tid & 63;
    int wr = (wave >> 1) * 64, wc = (wave & 1) * 64;
    int lm = lane & 15, lq = lane >> 4;

    f32x4 acc[4][4] = {};

    int srow = tid >> 2;
    int schunk = (tid & 3) * 8;

    for (int kt = 0; kt < K; kt += 32) {
#pragma unroll
        for (int p = 0; p < 2; p++) {
            int row = srow + p * 64;
            int grow = by * 128 + row;
            uint4 av = make_uint4(0u, 0u, 0u, 0u);
            if (grow < cnt) av = *(const uint4*)(Aseg + (size_t)grow * K + kt + schunk);
            *(uint4*)&As[row][schunk] = av;
            uint4 bv = *(const uint4*)(Bw + (size_t)row * K + kt + schunk);
            *(uint4*)&Bs[row][schunk] = bv;
        }
        __syncthreads();
        bf16x8 af[4], bfr[4];
#pragma unroll
        for (int i = 0; i < 4; i++) af[i] = *(const bf16x8*)&As[wr + i * 16 + lm][lq * 8];
#pragma unroll
        for (int j = 0; j < 4; j++) bfr[j] = *(const bf16x8*)&Bs[wc + j * 16 + lm][lq * 8];
#pragma unroll
        for (int i = 0; i < 4; i++)
#pragma unroll
            for (int j = 0; j < 4; j++)
                acc[i][j] = __builtin_amdgcn_mfma_f32_16x16x32_bf16(af[i], bfr[j], acc[i][j], 0, 0, 0);
        __syncthreads();
    }

#pragma unroll
    for (int j = 0; j < 4; j++) {
        int n = bx * 128 + wc + j * 16 + lm;
        float bv = bias[(size_t)e * N + n];
#pragma unroll
        for (int i = 0; i < 4; i++) {
#pragma unroll
            for (int r = 0; r < 4; r++) {
                int grow = by * 128 + wr + i * 16 + lq * 4 + r;
                if (grow < cnt) {
                    float v = acc[i][j][r] + bv;
                    if (RELU) v = fmaxf(v, 0.f);
                    if (!SCATTER) {
                        Cout[(size_t)(base + grow) * N + n] = f2bf(v);
                    } else {
                        int tok = pair_token[base + grow];
                        float pw = pair_w[base + grow];
                        atomicAdd(&outF[(size_t)tok * N + n], v * pw);
                    }
                }
            }
        }
    }
}

extern "C" void kernel_launch(void* const* d_in, const int* in_sizes, int n_in,
                              void* d_out, int out_size, void* d_ws, size_t ws_size,
                              hipStream_t stream) {
    const float* x      = (const float*)d_in[0];
    const float* genre  = (const float*)d_in[1];
    const float* rms_w  = (const float*)d_in[2];
    const float* wg_W   = (const float*)d_in[3];
    const float* wg_b   = (const float*)d_in[4];
    const float* gg_W   = (const float*)d_in[5];
    const float* gg_b   = (const float*)d_in[6];
    const float* W1     = (const float*)d_in[7];
    const float* b1     = (const float*)d_in[8];
    const float* W2     = (const float*)d_in[9];
    const float* b2     = (const float*)d_in[10];
    const float* W3     = (const float*)d_in[11];
    const float* b3     = (const float*)d_in[12];
    float* out = (float*)d_out;

    char* p = (char*)d_ws;
    auto alloc = [&](size_t bytes) { char* r = p; p += (bytes + 255) & ~(size_t)255; return r; };
    unsigned short* W1t = (unsigned short*)alloc((size_t)E_NUM * H_DIM * M_DIM * 2);
    unsigned short* W2t = (unsigned short*)alloc((size_t)E_NUM * M_DIM * M_DIM * 2);
    unsigned short* W3t = (unsigned short*)alloc((size_t)E_NUM * M_DIM * H_DIM * 2);
    unsigned short* x_g = (unsigned short*)alloc((size_t)N_PAIR * H_DIM * 2);
    unsigned short* h1  = (unsigned short*)alloc((size_t)N_PAIR * M_DIM * 2);
    unsigned short* h2  = (unsigned short*)alloc((size_t)N_PAIR * M_DIM * 2);
    float* genreE       = (float*)alloc(16 * 4);
    int*   meta         = (int*)alloc(24 * 4);      // counts[8], bases[8], fills[8]
    int*   tok_e        = (int*)alloc((size_t)N_PAIR * 4);
    float* tok_w        = (float*)alloc((size_t)N_PAIR * 4);
    int*   pair_token   = (int*)alloc((size_t)N_PAIR * 4);
    float* pair_w       = (float*)alloc((size_t)N_PAIR * 4);

    dim3 blk(256);

    // weight transpose+convert (independent of routing)
    k_transw<<<dim3(M_DIM / 32, H_DIM / 32, E_NUM), blk, 0, stream>>>(W1, W1t, H_DIM, M_DIM);
    k_transw<<<dim3(M_DIM / 32, M_DIM / 32, E_NUM), blk, 0, stream>>>(W2, W2t, M_DIM, M_DIM);
    k_transw<<<dim3(H_DIM / 32, M_DIM / 32, E_NUM), blk, 0, stream>>>(W3, W3t, M_DIM, H_DIM);

    hipMemsetAsync(d_out, 0, (size_t)out_size * sizeof(float), stream);

    k_init<<<1, 64, 0, stream>>>(genre, gg_W, gg_b, wg_b, genreE, meta);
    k_routing<<<T_TOK / 4, blk, 0, stream>>>(x, rms_w, wg_W, genreE, tok_e, tok_w, meta);
    k_scan<<<1, 64, 0, stream>>>(meta);
    k_gather<<<N_PAIR / 4, blk, 0, stream>>>(x, tok_e, tok_w, meta, pair_token, pair_w, x_g);

    // expert GEMMs: worst-case 32 row tiles per expert, early-exit on count
    k_gemm<true,  false><<<dim3(M_DIM / 128, 32, E_NUM), blk, 0, stream>>>(
        x_g, W1t, b1, h1, nullptr, meta, nullptr, nullptr, H_DIM, M_DIM);
    k_gemm<true,  false><<<dim3(M_DIM / 128, 32, E_NUM), blk, 0, stream>>>(
        h1, W2t, b2, h2, nullptr, meta, nullptr, nullptr, M_DIM, M_DIM);
    k_gemm<false, true><<<dim3(H_DIM / 128, 32, E_NUM), blk, 0, stream>>>(
        h2, W3t, b3, nullptr, out, meta, pair_token, pair_w, M_DIM, H_DIM);

    (void)in_sizes; (void)n_in; (void)ws_size;
}

// Round 2
// 852.710 us; speedup vs baseline: 1.0922x; 1.0922x over previous
//
#include <hip/hip_runtime.h>
#include <hip/hip_bf16.h>

// Problem constants: B=2, S=2048, H=1024, G=256, E=8, M=2048, TOP_K=2
#define T_TOK 4096      // B*S
#define N_PAIR 8192     // T_TOK * 2
#define H_DIM 1024
#define M_DIM 2048
#define E_NUM 8

using bf16x8 = __attribute__((ext_vector_type(8))) short;
using f32x4  = __attribute__((ext_vector_type(4))) float;

__device__ __forceinline__ unsigned short f2bf(float f) {
    unsigned int u = __builtin_bit_cast(unsigned int, f);
    u += 0x7fffu + ((u >> 16) & 1u);   // RNE
    return (unsigned short)(u >> 16);
}

// async global->LDS, 16B per lane; LDS dest is wave-uniform base + lane*16
__device__ __forceinline__ void async16(const unsigned short* g, unsigned short* l) {
    __builtin_amdgcn_global_load_lds(
        (const __attribute__((address_space(1))) void*)g,
        (__attribute__((address_space(3))) void*)l, 16, 0, 0);
}

// ---- K0: genre gate per (b,e) with both biases folded; zero meta[24] ----
__global__ void k_init(const float* __restrict__ genre, const float* __restrict__ gg_W,
                       const float* __restrict__ gg_b, const float* __restrict__ wg_b,
                       float* __restrict__ genreE, int* __restrict__ meta)
{
    int t = threadIdx.x;
    if (t < 16) {
        int b = t >> 3, e = t & 7;
        float s = wg_b[e] + gg_b[e];
        for (int gi = 0; gi < 256; gi++) s += genre[b * 256 + gi] * gg_W[gi * 8 + e];
        genreE[t] = s;
    }
    if (t >= 32 && t < 56) meta[t - 32] = 0;  // counts[8], bases[8], fills[8]
}

// ---- K1: RMSNorm + word gate + softmax + top2. One wave per token. ----
__global__ void k_routing(const float* __restrict__ x, const float* __restrict__ rms_w,
                          const float* __restrict__ wg_W, const float* __restrict__ genreE,
                          int* __restrict__ tok_e, float* __restrict__ tok_w,
                          int* __restrict__ meta)
{
    int wave = threadIdx.x >> 6, lane = threadIdx.x & 63;
    int t = blockIdx.x * 4 + wave;
    const float* xr = x + (size_t)t * H_DIM;
    float xv[16];
    float ss = 0.f;
#pragma unroll
    for (int j = 0; j < 16; j++) { xv[j] = xr[lane + 64 * j]; ss += xv[j] * xv[j]; }
#pragma unroll
    for (int off = 32; off > 0; off >>= 1) ss += __shfl_xor(ss, off);
    float rstd = rsqrtf(ss * (1.f / 1024.f) + 1e-6f);
    float g[8] = {0.f, 0.f, 0.f, 0.f, 0.f, 0.f, 0.f, 0.f};
#pragma unroll
    for (int j = 0; j < 16; j++) {
        int h = lane + 64 * j;
        float xn = xv[j] * rstd * rms_w[h];
        const float4* w4 = (const float4*)(wg_W + h * 8);
        float4 wa = w4[0], wb = w4[1];
        g[0] += xn * wa.x; g[1] += xn * wa.y; g[2] += xn * wa.z; g[3] += xn * wa.w;
        g[4] += xn * wb.x; g[5] += xn * wb.y; g[6] += xn * wb.z; g[7] += xn * wb.w;
    }
#pragma unroll
    for (int e = 0; e < 8; e++) {
#pragma unroll
        for (int off = 32; off > 0; off >>= 1) g[e] += __shfl_xor(g[e], off);
    }
    if (lane == 0) {
        int b = t >> 11;
#pragma unroll
        for (int e = 0; e < 8; e++) g[e] += genreE[b * 8 + e];
        float m = g[0];
        for (int e = 1; e < 8; e++) m = fmaxf(m, g[e]);
        float p[8], psum = 0.f;
        for (int e = 0; e < 8; e++) { p[e] = expf(g[e] - m); psum += p[e]; }
        int i0 = 0;
        for (int e = 1; e < 8; e++) if (p[e] > p[i0]) i0 = e;
        int i1 = (i0 == 0) ? 1 : 0;
        for (int e = 0; e < 8; e++) if (e != i0 && p[e] > p[i1]) i1 = e;
        float inv = 1.f / psum;
        tok_e[t * 2] = i0;     tok_e[t * 2 + 1] = i1;
        tok_w[t * 2] = p[i0] * inv; tok_w[t * 2 + 1] = p[i1] * inv;
        atomicAdd(&meta[i0], 1);
        atomicAdd(&meta[i1], 1);
    }
}

// ---- K2: exclusive prefix sum over 8 counts ----
__global__ void k_scan(int* __restrict__ meta)
{
    if (threadIdx.x == 0) {
        int acc = 0;
        for (int e = 0; e < 8; e++) { meta[8 + e] = acc; meta[16 + e] = acc; acc += meta[e]; }
    }
}

// ---- K3: gather token rows (fp32 -> bf16) into expert-sorted order; record pos ----
__global__ void k_gather(const float* __restrict__ x, const int* __restrict__ tok_e,
                         int* __restrict__ meta, int* __restrict__ pair_pos,
                         unsigned short* __restrict__ x_g)
{
    int wave = threadIdx.x >> 6, lane = threadIdx.x & 63;
    int p = blockIdx.x * 4 + wave;
    int t = p >> 1;
    int e = tok_e[p];
    int pos;
    if (lane == 0) {
        pos = atomicAdd(&meta[16 + e], 1);
        pair_pos[p] = pos;
    }
    pos = __shfl(pos, 0);
    const float4* src = (const float4*)(x + (size_t)t * H_DIM);
    ushort4* dst = (ushort4*)(x_g + (size_t)pos * H_DIM);
#pragma unroll
    for (int j = 0; j < 4; j++) {
        float4 v = src[lane + 64 * j];
        ushort4 o;
        o.x = f2bf(v.x); o.y = f2bf(v.y); o.z = f2bf(v.z); o.w = f2bf(v.w);
        dst[lane + 64 * j] = o;
    }
}

// ---- K4: transpose-convert weights [E][K][N] fp32 -> [E][N][K] bf16 ----
__global__ void k_transw(const float* __restrict__ W, unsigned short* __restrict__ Wt,
                         int K, int N)
{
    __shared__ float ld[32][33];
    size_t eoff = (size_t)blockIdx.z * K * N;
    int k0 = blockIdx.y * 32, n0 = blockIdx.x * 32;
    int t = threadIdx.x;
    {
        int kk = t >> 3, nc = t & 7;
        float4 v = *(const float4*)(W + eoff + (size_t)(k0 + kk) * N + n0 + nc * 4);
        ld[kk][nc * 4 + 0] = v.x; ld[kk][nc * 4 + 1] = v.y;
        ld[kk][nc * 4 + 2] = v.z; ld[kk][nc * 4 + 3] = v.w;
    }
    __syncthreads();
    {
        int nn = t >> 3, kc = t & 7;
        ushort4 o;
        o.x = f2bf(ld[kc * 4 + 0][nn]); o.y = f2bf(ld[kc * 4 + 1][nn]);
        o.z = f2bf(ld[kc * 4 + 2][nn]); o.w = f2bf(ld[kc * 4 + 3][nn]);
        *(ushort4*)(Wt + eoff + (size_t)(n0 + nn) * K + k0 + kc * 4) = o;
    }
}

// ---- GEMM: C[seg rows x N] = A_seg @ Wt[e]^T (+bias, optional relu) ----
// m97-style: global_load_lds width-16 staging into unpadded [128][32] LDS tiles,
// 4 waves x (4x4 of 16x16x32 bf16 MFMA), 2 barriers per K-step.
template<bool RELU, bool F32OUT>
__global__ void k_gemm(const unsigned short* __restrict__ A,
                       const unsigned short* __restrict__ Wt,
                       const float* __restrict__ bias,
                       unsigned short* __restrict__ Cb,
                       float* __restrict__ Cf,
                       const int* __restrict__ meta,
                       int K, int N)
{
    int e = blockIdx.z;
    int cnt = meta[e];
    int by = blockIdx.y;
    if (by * 128 >= cnt) return;
    int base = meta[8 + e];
    int bx = blockIdx.x;

    __shared__ __align__(16) unsigned short As[128 * 32];
    __shared__ __align__(16) unsigned short Bs[128 * 32];

    int tid = threadIdx.x;
    int wave = tid >> 6, lane = tid & 63;

    // staging: each wave covers 16 rows (64B/row) per pass; lane -> (row, 16B chunk)
    int lrow = lane >> 2;
    int lchunk = (lane & 3) * 8;   // in shorts

    int arow0 = base + by * 128 + wave * 16 + lrow;
    int arow1 = arow0 + 64;
    arow0 = min(arow0, N_PAIR - 1);   // clamp: stay in-bounds, garbage rows discarded
    arow1 = min(arow1, N_PAIR - 1);
    const unsigned short* ga0 = A + (size_t)arow0 * K + lchunk;
    const unsigned short* ga1 = A + (size_t)arow1 * K + lchunk;

    const unsigned short* Bw = Wt + (size_t)e * N * K + (size_t)(bx * 128) * K;
    const unsigned short* gb0 = Bw + (size_t)(wave * 16 + lrow) * K + lchunk;
    const unsigned short* gb1 = gb0 + (size_t)64 * K;

    unsigned short* lA0 = &As[(wave * 16) * 32];
    unsigned short* lA1 = &As[(64 + wave * 16) * 32];
    unsigned short* lB0 = &Bs[(wave * 16) * 32];
    unsigned short* lB1 = &Bs[(64 + wave * 16) * 32];

    int wr = (wave >> 1) * 64, wc = (wave & 1) * 64;
    int lm = lane & 15, lq = lane >> 4;

    f32x4 acc[4][4] = {};

    for (int kt = 0; kt < K; kt += 32) {
        async16(ga0 + kt, lA0);
        async16(ga1 + kt, lA1);
        async16(gb0 + kt, lB0);
        async16(gb1 + kt, lB1);
        __syncthreads();
        bf16x8 af[4], bfr[4];
#pragma unroll
        for (int i = 0; i < 4; i++) af[i] = *(const bf16x8*)&As[(wr + i * 16 + lm) * 32 + lq * 8];
#pragma unroll
        for (int j = 0; j < 4; j++) bfr[j] = *(const bf16x8*)&Bs[(wc + j * 16 + lm) * 32 + lq * 8];
#pragma unroll
        for (int i = 0; i < 4; i++)
#pragma unroll
            for (int j = 0; j < 4; j++)
                acc[i][j] = __builtin_amdgcn_mfma_f32_16x16x32_bf16(af[i], bfr[j], acc[i][j], 0, 0, 0);
        __syncthreads();
    }

#pragma unroll
    for (int j = 0; j < 4; j++) {
        int n = bx * 128 + wc + j * 16 + lm;
        float bv = bias[(size_t)e * N + n];
#pragma unroll
        for (int i = 0; i < 4; i++) {
#pragma unroll
            for (int r = 0; r < 4; r++) {
                int grow = by * 128 + wr + i * 16 + lq * 4 + r;
                if (grow < cnt) {
                    float v = acc[i][j][r] + bv;
                    if (RELU) v = fmaxf(v, 0.f);
                    if (F32OUT) Cf[(size_t)(base + grow) * N + n] = v;
                    else        Cb[(size_t)(base + grow) * N + n] = f2bf(v);
                }
            }
        }
    }
}

// ---- K5: combine: out[t] = w0*o3[pos(t,0)] + w1*o3[pos(t,1)] ----
__global__ void k_combine(const float* __restrict__ o3, const int* __restrict__ pair_pos,
                          const float* __restrict__ tok_w, float* __restrict__ out)
{
    int t = blockIdx.x;
    int c = threadIdx.x;                 // 256 threads x float4 = 1024
    int p0 = pair_pos[t * 2], p1 = pair_pos[t * 2 + 1];
    float w0 = tok_w[t * 2], w1 = tok_w[t * 2 + 1];
    float4 a = ((const float4*)(o3 + (size_t)p0 * H_DIM))[c];
    float4 b = ((const float4*)(o3 + (size_t)p1 * H_DIM))[c];
    float4 o;
    o.x = w0 * a.x + w1 * b.x;
    o.y = w0 * a.y + w1 * b.y;
    o.z = w0 * a.z + w1 * b.z;
    o.w = w0 * a.w + w1 * b.w;
    ((float4*)(out + (size_t)t * H_DIM))[c] = o;
}

extern "C" void kernel_launch(void* const* d_in, const int* in_sizes, int n_in,
                              void* d_out, int out_size, void* d_ws, size_t ws_size,
                              hipStream_t stream) {
    const float* x      = (const float*)d_in[0];
    const float* genre  = (const float*)d_in[1];
    const float* rms_w  = (const float*)d_in[2];
    const float* wg_W   = (const float*)d_in[3];
    const float* wg_b   = (const float*)d_in[4];
    const float* gg_W   = (const float*)d_in[5];
    const float* gg_b   = (const float*)d_in[6];
    const float* W1     = (const float*)d_in[7];
    const float* b1     = (const float*)d_in[8];
    const float* W2     = (const float*)d_in[9];
    const float* b2     = (const float*)d_in[10];
    const float* W3     = (const float*)d_in[11];
    const float* b3     = (const float*)d_in[12];
    float* out = (float*)d_out;

    char* p = (char*)d_ws;
    auto alloc = [&](size_t bytes) { char* r = p; p += (bytes + 255) & ~(size_t)255; return r; };
    unsigned short* W1t = (unsigned short*)alloc((size_t)E_NUM * H_DIM * M_DIM * 2);
    unsigned short* W2t = (unsigned short*)alloc((size_t)E_NUM * M_DIM * M_DIM * 2);
    unsigned short* W3t = (unsigned short*)alloc((size_t)E_NUM * M_DIM * H_DIM * 2);
    unsigned short* x_g = (unsigned short*)alloc((size_t)N_PAIR * H_DIM * 2);
    unsigned short* h1  = (unsigned short*)alloc((size_t)N_PAIR * M_DIM * 2);
    unsigned short* h2  = (unsigned short*)alloc((size_t)N_PAIR * M_DIM * 2);
    float* o3           = (float*)alloc((size_t)N_PAIR * H_DIM * 4);
    float* genreE       = (float*)alloc(16 * 4);
    int*   meta         = (int*)alloc(24 * 4);      // counts[8], bases[8], fills[8]
    int*   tok_e        = (int*)alloc((size_t)N_PAIR * 4);
    float* tok_w        = (float*)alloc((size_t)N_PAIR * 4);
    int*   pair_pos     = (int*)alloc((size_t)N_PAIR * 4);

    dim3 blk(256);

    // weight transpose+convert (independent of routing)
    k_transw<<<dim3(M_DIM / 32, H_DIM / 32, E_NUM), blk, 0, stream>>>(W1, W1t, H_DIM, M_DIM);
    k_transw<<<dim3(M_DIM / 32, M_DIM / 32, E_NUM), blk, 0, stream>>>(W2, W2t, M_DIM, M_DIM);
    k_transw<<<dim3(H_DIM / 32, M_DIM / 32, E_NUM), blk, 0, stream>>>(W3, W3t, M_DIM, H_DIM);

    k_init<<<1, 64, 0, stream>>>(genre, gg_W, gg_b, wg_b, genreE, meta);
    k_routing<<<T_TOK / 4, blk, 0, stream>>>(x, rms_w, wg_W, genreE, tok_e, tok_w, meta);
    k_scan<<<1, 64, 0, stream>>>(meta);
    k_gather<<<N_PAIR / 4, blk, 0, stream>>>(x, tok_e, meta, pair_pos, x_g);

    // expert GEMMs: worst-case 32 row tiles per expert, early-exit on count
    k_gemm<true,  false><<<dim3(M_DIM / 128, 32, E_NUM), blk, 0, stream>>>(
        x_g, W1t, b1, h1, nullptr, meta, H_DIM, M_DIM);
    k_gemm<true,  false><<<dim3(M_DIM / 128, 32, E_NUM), blk, 0, stream>>>(
        h1, W2t, b2, h2, nullptr, meta, M_DIM, M_DIM);
    k_gemm<false, true><<<dim3(H_DIM / 128, 32, E_NUM), blk, 0, stream>>>(
        h2, W3t, b3, nullptr, o3, meta, M_DIM, H_DIM);

    k_combine<<<T_TOK, blk, 0, stream>>>(o3, pair_pos, tok_w, out);

    (void)in_sizes; (void)n_in; (void)ws_size;
}

// Round 3
// 699.423 us; speedup vs baseline: 1.3315x; 1.2192x over previous
//
#include <hip/hip_runtime.h>
#include <hip/hip_bf16.h>

// Problem constants: B=2, S=2048, H=1024, G=256, E=8, M=2048, TOP_K=2
#define T_TOK 4096      // B*S
#define N_PAIR 8192     // T_TOK * 2
#define H_DIM 1024
#define M_DIM 2048
#define E_NUM 8

// prep-kernel block ranges
#define T_W1 4096       // (E*H/32)*(M/128) = 256*16
#define T_W2 8192       // (E*M/32)*(M/128) = 512*16
#define T_W3 4096       // (E*M/32)*(H/128) = 512*8
#define T_ROUT 1024     // 4096 tokens / 4 waves

using bf16x8 = __attribute__((ext_vector_type(8))) short;
using f32x4  = __attribute__((ext_vector_type(4))) float;

__device__ __forceinline__ unsigned short f2bf(float f) {
    unsigned int u = __builtin_bit_cast(unsigned int, f);
    u += 0x7fffu + ((u >> 16) & 1u);   // RNE
    return (unsigned short)(u >> 16);
}
__device__ __forceinline__ float bf2f(unsigned short u) {
    return __builtin_bit_cast(float, (unsigned int)u << 16);
}

// async global->LDS, 16B per lane; LDS dest is wave-uniform base + lane*16
__device__ __forceinline__ void async16(const unsigned short* g, unsigned short* l) {
    __builtin_amdgcn_global_load_lds(
        (const __attribute__((address_space(1))) void*)g,
        (__attribute__((address_space(3))) void*)l, 16, 0, 0);
}

// ---- K_prep: fused weight transposes (blocks [0, T_W1+T_W2+T_W3)) + routing ----
__global__ void k_prep(const float* __restrict__ W1, const float* __restrict__ W2,
                       const float* __restrict__ W3,
                       unsigned short* __restrict__ W1t, unsigned short* __restrict__ W2t,
                       unsigned short* __restrict__ W3t,
                       const float* __restrict__ x, const float* __restrict__ rms_w,
                       const float* __restrict__ wg_W, const float* __restrict__ genre,
                       const float* __restrict__ gg_W, const float* __restrict__ gg_b,
                       const float* __restrict__ wg_b,
                       int* __restrict__ tok_e, float* __restrict__ tok_w)
{
    __shared__ float ld[32][132];   // pad 132: conflict-free read+write phases
    int bid = blockIdx.x;

    if (bid < T_W1 + T_W2 + T_W3) {
        // ---- transpose-convert one [32k x 128n] tile: W [E*K][N] fp32 -> Wt [E][N][K] bf16
        const float* W; unsigned short* Wt; int tile, kshift, ntshift, N, K;
        if (bid < T_W1)              { W = W1; Wt = W1t; tile = bid;                 K = H_DIM; N = M_DIM; kshift = 10; ntshift = 4; }
        else if (bid < T_W1 + T_W2)  { W = W2; Wt = W2t; tile = bid - T_W1;          K = M_DIM; N = M_DIM; kshift = 11; ntshift = 4; }
        else                         { W = W3; Wt = W3t; tile = bid - T_W1 - T_W2;   K = M_DIM; N = H_DIM; kshift = 11; ntshift = 3; }
        int r0 = (tile >> ntshift) * 32;                  // global row in [0, E*K)
        int n0 = (tile & ((1 << ntshift) - 1)) * 128;
        int t = threadIdx.x;
        // phase 1: 32 rows x 128 floats; 8 threads/row x 4 float4 each
        {
            int rr = t >> 3, c0 = t & 7;
            const float4* src = (const float4*)(W + (size_t)(r0 + rr) * N + n0);
#pragma unroll
            for (int cc = 0; cc < 4; cc++) {
                float4 v = src[c0 + cc * 8];
                float* d = &ld[rr][(c0 + cc * 8) * 4];
                d[0] = v.x; d[1] = v.y; d[2] = v.z; d[3] = v.w;
            }
        }
        __syncthreads();
        // phase 2: write [128n][32k] bf16; thread -> (n = t>>1, k-half = t&1 -> 16 k)
        {
            int n = t >> 1, half = t & 1;
            int kb = half * 16;
            bf16x8 o0, o1;
#pragma unroll
            for (int q = 0; q < 8; q++) o0[q] = (short)f2bf(ld[kb + q][n]);
#pragma unroll
            for (int q = 0; q < 8; q++) o1[q] = (short)f2bf(ld[kb + 8 + q][n]);
            int rg = r0 + kb;
            int e = rg >> kshift;
            int k = rg & (K - 1);
            unsigned short* dst = Wt + ((size_t)e * N + (n0 + n)) * K + k;
            *(bf16x8*)dst = o0;
            *(bf16x8*)(dst + 8) = o1;
        }
        return;
    }

    // ---- routing: RMSNorm + word gate + genre gate + softmax + top2 ----
    int wave = threadIdx.x >> 6, lane = threadIdx.x & 63;
    int tok = (bid - (T_W1 + T_W2 + T_W3)) * 4 + wave;
    int b = tok >> 11;
    const float* xr = x + (size_t)tok * H_DIM;
    float xv[16];
    float ss = 0.f;
#pragma unroll
    for (int j = 0; j < 16; j++) { xv[j] = xr[lane + 64 * j]; ss += xv[j] * xv[j]; }
#pragma unroll
    for (int off = 32; off > 0; off >>= 1) ss += __shfl_xor(ss, off);
    float rstd = rsqrtf(ss * (1.f / 1024.f) + 1e-6f);
    // genre-gate partial folded into g[] before reduction
    float g[8] = {0.f, 0.f, 0.f, 0.f, 0.f, 0.f, 0.f, 0.f};
#pragma unroll
    for (int gi0 = 0; gi0 < 4; gi0++) {
        int gi = lane + gi0 * 64;
        float gf = genre[b * 256 + gi];
        const float4* w4 = (const float4*)(gg_W + gi * 8);
        float4 wa = w4[0], wb = w4[1];
        g[0] += gf * wa.x; g[1] += gf * wa.y; g[2] += gf * wa.z; g[3] += gf * wa.w;
        g[4] += gf * wb.x; g[5] += gf * wb.y; g[6] += gf * wb.z; g[7] += gf * wb.w;
    }
#pragma unroll
    for (int j = 0; j < 16; j++) {
        int h = lane + 64 * j;
        float xn = xv[j] * rstd * rms_w[h];
        const float4* w4 = (const float4*)(wg_W + h * 8);
        float4 wa = w4[0], wb = w4[1];
        g[0] += xn * wa.x; g[1] += xn * wa.y; g[2] += xn * wa.z; g[3] += xn * wa.w;
        g[4] += xn * wb.x; g[5] += xn * wb.y; g[6] += xn * wb.z; g[7] += xn * wb.w;
    }
#pragma unroll
    for (int e = 0; e < 8; e++) {
#pragma unroll
        for (int off = 32; off > 0; off >>= 1) g[e] += __shfl_xor(g[e], off);
    }
    if (lane == 0) {
#pragma unroll
        for (int e = 0; e < 8; e++) g[e] += wg_b[e] + gg_b[e];
        float m = g[0];
        for (int e = 1; e < 8; e++) m = fmaxf(m, g[e]);
        float p[8], psum = 0.f;
        for (int e = 0; e < 8; e++) { p[e] = expf(g[e] - m); psum += p[e]; }
        int i0 = 0;
        for (int e = 1; e < 8; e++) if (p[e] > p[i0]) i0 = e;
        int i1 = (i0 == 0) ? 1 : 0;
        for (int e = 0; e < 8; e++) if (e != i0 && p[e] > p[i1]) i1 = e;
        float inv = 1.f / psum;
        tok_e[tok * 2] = i0;         tok_e[tok * 2 + 1] = i1;
        tok_w[tok * 2] = p[i0] * inv; tok_w[tok * 2 + 1] = p[i1] * inv;
    }
}

// ---- K_scan: histogram tok_e + exclusive scan (single block) ----
__global__ void k_scan(const int* __restrict__ tok_e, int* __restrict__ meta)
{
    __shared__ int cnt[8];
    int t = threadIdx.x;
    if (t < 8) cnt[t] = 0;
    __syncthreads();
    for (int p = t; p < N_PAIR; p += 256) atomicAdd(&cnt[tok_e[p]], 1);
    __syncthreads();
    if (t == 0) {
        int acc = 0;
        for (int e = 0; e < 8; e++) {
            meta[e] = cnt[e]; meta[8 + e] = acc; meta[16 + e] = acc; acc += cnt[e];
        }
    }
}

// ---- K_gather: gather token rows (fp32 -> bf16) into expert-sorted order ----
__global__ void k_gather(const float* __restrict__ x, const int* __restrict__ tok_e,
                         int* __restrict__ meta, int* __restrict__ pair_pos,
                         unsigned short* __restrict__ x_g)
{
    int wave = threadIdx.x >> 6, lane = threadIdx.x & 63;
    int p = blockIdx.x * 4 + wave;
    int t = p >> 1;
    int e = tok_e[p];
    int pos;
    if (lane == 0) {
        pos = atomicAdd(&meta[16 + e], 1);
        pair_pos[p] = pos;
    }
    pos = __shfl(pos, 0);
    const float4* src = (const float4*)(x + (size_t)t * H_DIM);
    ushort4* dst = (ushort4*)(x_g + (size_t)pos * H_DIM);
#pragma unroll
    for (int j = 0; j < 4; j++) {
        float4 v = src[lane + 64 * j];
        ushort4 o;
        o.x = f2bf(v.x); o.y = f2bf(v.y); o.z = f2bf(v.z); o.w = f2bf(v.w);
        dst[lane + 64 * j] = o;
    }
}

// ---- GEMM: C = A_seg @ Wt[e]^T (+bias, optional relu), bf16 out ----
// BK=64 K-loop (half the barriers of BK=32), global_load_lds width-16 staging,
// XOR-swizzled unpadded LDS (wave-uniform dest constraint): LDS slot s of row r
// holds global chunk s^(r&7); read side XORs identically -> conflict-free b128 reads.
template<bool RELU>
__global__ void k_gemm(const unsigned short* __restrict__ A,
                       const unsigned short* __restrict__ Wt,
                       const float* __restrict__ bias,
                       unsigned short* __restrict__ C,
                       const int* __restrict__ meta,
                       int K, int N)
{
    int e = blockIdx.z;
    int cnt = meta[e];
    int by = blockIdx.y;
    if (by * 128 >= cnt) return;
    int base = meta[8 + e];
    int bx = blockIdx.x;

    __shared__ __align__(16) unsigned short As[128 * 64];
    __shared__ __align__(16) unsigned short Bs[128 * 64];

    int tid = threadIdx.x;
    int wave = tid >> 6, lane = tid & 63;
    int lrow8 = lane >> 3;                      // 0..7: row within 8-row staging group
    int lslot = lane & 7;                       // LDS chunk slot
    int chunk_g = (lslot ^ lrow8) * 8;          // global chunk offset (shorts)

    const unsigned short* Bw = Wt + (size_t)e * N * K + (size_t)(bx * 128) * K;
    const unsigned short* gA[4]; const unsigned short* gB[4];
    unsigned short* lA[4]; unsigned short* lB[4];
#pragma unroll
    for (int c = 0; c < 4; c++) {
        int rloc = wave * 32 + c * 8 + lrow8;
        int ra = base + by * 128 + rloc;
        ra = min(ra, N_PAIR - 1);               // clamp: garbage rows discarded in epilogue
        gA[c] = A + (size_t)ra * K + chunk_g;
        gB[c] = Bw + (size_t)rloc * K + chunk_g;
        lA[c] = &As[(wave * 32 + c * 8) * 64];
        lB[c] = &Bs[(wave * 32 + c * 8) * 64];
    }

    int wr = (wave >> 1) * 64, wc = (wave & 1) * 64;
    int lm = lane & 15, lq = lane >> 4;

    // fixed LDS read offsets (shorts): frag (i, k-half h)
    int aoff[4][2], boff[4][2];
#pragma unroll
    for (int i = 0; i < 4; i++)
#pragma unroll
        for (int h = 0; h < 2; h++) {
            int R = wr + i * 16 + lm;
            aoff[i][h] = R * 64 + (((h * 4 + lq) ^ (R & 7)) * 8);
            int Nn = wc + i * 16 + lm;
            boff[i][h] = Nn * 64 + (((h * 4 + lq) ^ (Nn & 7)) * 8);
        }

    f32x4 acc[4][4] = {};

    for (int kt = 0; kt < K; kt += 64) {
#pragma unroll
        for (int c = 0; c < 4; c++) { async16(gA[c] + kt, lA[c]); async16(gB[c] + kt, lB[c]); }
        __syncthreads();
#pragma unroll
        for (int h = 0; h < 2; h++) {
            bf16x8 af[4], bfr[4];
#pragma unroll
            for (int i = 0; i < 4; i++) af[i] = *(const bf16x8*)&As[aoff[i][h]];
#pragma unroll
            for (int j = 0; j < 4; j++) bfr[j] = *(const bf16x8*)&Bs[boff[j][h]];
#pragma unroll
            for (int i = 0; i < 4; i++)
#pragma unroll
                for (int j = 0; j < 4; j++)
                    acc[i][j] = __builtin_amdgcn_mfma_f32_16x16x32_bf16(af[i], bfr[j], acc[i][j], 0, 0, 0);
        }
        __syncthreads();
    }

#pragma unroll
    for (int j = 0; j < 4; j++) {
        int n = bx * 128 + wc + j * 16 + lm;
        float bv = bias[(size_t)e * N + n];
#pragma unroll
        for (int i = 0; i < 4; i++) {
#pragma unroll
            for (int r = 0; r < 4; r++) {
                int grow = by * 128 + wr + i * 16 + lq * 4 + r;
                if (grow < cnt) {
                    float v = acc[i][j][r] + bv;
                    if (RELU) v = fmaxf(v, 0.f);
                    C[(size_t)(base + grow) * N + n] = f2bf(v);
                }
            }
        }
    }
}

// ---- K_combine: out[t] = w0*o3[pos(t,0)] + w1*o3[pos(t,1)] (o3 bf16) ----
__global__ void k_combine(const unsigned short* __restrict__ o3,
                          const int* __restrict__ pair_pos,
                          const float* __restrict__ tok_w, float* __restrict__ out)
{
    int t = blockIdx.x;
    int c = threadIdx.x;                 // 256 threads x 4 elems = 1024
    int p0 = pair_pos[t * 2], p1 = pair_pos[t * 2 + 1];
    float w0 = tok_w[t * 2], w1 = tok_w[t * 2 + 1];
    ushort4 a = ((const ushort4*)(o3 + (size_t)p0 * H_DIM))[c];
    ushort4 bq = ((const ushort4*)(o3 + (size_t)p1 * H_DIM))[c];
    float4 o;
    o.x = w0 * bf2f(a.x) + w1 * bf2f(bq.x);
    o.y = w0 * bf2f(a.y) + w1 * bf2f(bq.y);
    o.z = w0 * bf2f(a.z) + w1 * bf2f(bq.z);
    o.w = w0 * bf2f(a.w) + w1 * bf2f(bq.w);
    ((float4*)(out + (size_t)t * H_DIM))[c] = o;
}

extern "C" void kernel_launch(void* const* d_in, const int* in_sizes, int n_in,
                              void* d_out, int out_size, void* d_ws, size_t ws_size,
                              hipStream_t stream) {
    const float* x      = (const float*)d_in[0];
    const float* genre  = (const float*)d_in[1];
    const float* rms_w  = (const float*)d_in[2];
    const float* wg_W   = (const float*)d_in[3];
    const float* wg_b   = (const float*)d_in[4];
    const float* gg_W   = (const float*)d_in[5];
    const float* gg_b   = (const float*)d_in[6];
    const float* W1     = (const float*)d_in[7];
    const float* b1     = (const float*)d_in[8];
    const float* W2     = (const float*)d_in[9];
    const float* b2     = (const float*)d_in[10];
    const float* W3     = (const float*)d_in[11];
    const float* b3     = (const float*)d_in[12];
    float* out = (float*)d_out;

    char* p = (char*)d_ws;
    auto alloc = [&](size_t bytes) { char* r = p; p += (bytes + 255) & ~(size_t)255; return r; };
    unsigned short* W1t = (unsigned short*)alloc((size_t)E_NUM * H_DIM * M_DIM * 2);
    unsigned short* W2t = (unsigned short*)alloc((size_t)E_NUM * M_DIM * M_DIM * 2);
    unsigned short* W3t = (unsigned short*)alloc((size_t)E_NUM * M_DIM * H_DIM * 2);
    unsigned short* x_g = (unsigned short*)alloc((size_t)N_PAIR * H_DIM * 2);
    unsigned short* h1  = (unsigned short*)alloc((size_t)N_PAIR * M_DIM * 2);
    unsigned short* h2  = (unsigned short*)alloc((size_t)N_PAIR * M_DIM * 2);
    unsigned short* o3  = (unsigned short*)alloc((size_t)N_PAIR * H_DIM * 2);
    int*   meta         = (int*)alloc(24 * 4);      // counts[8], bases[8], fills[8]
    int*   tok_e        = (int*)alloc((size_t)N_PAIR * 4);
    float* tok_w        = (float*)alloc((size_t)N_PAIR * 4);
    int*   pair_pos     = (int*)alloc((size_t)N_PAIR * 4);

    dim3 blk(256);

    k_prep<<<T_W1 + T_W2 + T_W3 + T_ROUT, blk, 0, stream>>>(
        W1, W2, W3, W1t, W2t, W3t, x, rms_w, wg_W, genre, gg_W, gg_b, wg_b,
        tok_e, tok_w);
    k_scan<<<1, blk, 0, stream>>>(tok_e, meta);
    k_gather<<<N_PAIR / 4, blk, 0, stream>>>(x, tok_e, meta, pair_pos, x_g);

    // expert GEMMs: worst-case 32 row tiles per expert, early-exit on count
    k_gemm<true ><<<dim3(M_DIM / 128, 32, E_NUM), blk, 0, stream>>>(
        x_g, W1t, b1, h1, meta, H_DIM, M_DIM);
    k_gemm<true ><<<dim3(M_DIM / 128, 32, E_NUM), blk, 0, stream>>>(
        h1, W2t, b2, h2, meta, M_DIM, M_DIM);
    k_gemm<false><<<dim3(H_DIM / 128, 32, E_NUM), blk, 0, stream>>>(
        h2, W3t, b3, o3, meta, M_DIM, H_DIM);

    k_combine<<<T_TOK, blk, 0, stream>>>(o3, pair_pos, tok_w, out);

    (void)in_sizes; (void)n_in; (void)ws_size;
}